// Round 19
// baseline (456.732 us; speedup 1.0000x reference)
//
#include <hip/hip_runtime.h>
#include <math.h>

// WheelMultiheadAttention on MI355X (gfx950) — v20: barrier-free autonomous-wave attention.
// Each wave owns (bh, 16 q-rows) x ALL 2048 k. Pass A: row sums only (no P kept), in-wave
// shfl reduce -> rz (no __syncthreads). Pass B: recompute QK, exp, pstage-transposed 512B NT
// stores + PV. Whole grid co-resident -> waves free-run -> continuous store issue.
// v18 probe: NT path = 5.74 TB/s; v14's 3.3 TB/s effective was phase lockstep.
// B=2 T=2048 C=1024 H=16 D=64. Outputs: out [2,2048,1024] f32, weights [2,16,2048,2048] f32.

typedef _Float16 f16;
typedef _Float16 f16x2 __attribute__((ext_vector_type(2)));
typedef _Float16 f16x4 __attribute__((ext_vector_type(4)));
typedef _Float16 f16x8 __attribute__((ext_vector_type(8)));
typedef float  f32x2  __attribute__((ext_vector_type(2)));
typedef float  f32x4  __attribute__((ext_vector_type(4)));

#define MFMAH(a, b, c)  __builtin_amdgcn_mfma_f32_16x16x32_f16((a), (b), (c), 0, 0, 0)

__device__ __forceinline__ void gload16(void* lds, const void* g) {
  __builtin_amdgcn_global_load_lds((__attribute__((address_space(1))) void*)(g),
                                   (__attribute__((address_space(3))) void*)(lds),
                                   16, 0, 0);
}

// ---------------- fused f32 -> f16 convert (query|key|value|q_w|k_w|v_w|o_w) ----------------
__global__ __launch_bounds__(256) void conv_f16(const float* __restrict__ q, const float* __restrict__ k,
                                                const float* __restrict__ v, const float* __restrict__ qw,
                                                const float* __restrict__ kw, const float* __restrict__ vw,
                                                const float* __restrict__ ow, f16* __restrict__ xf) {
  long long i = ((long long)blockIdx.x * 256 + threadIdx.x) * 4;
  const float* src;
  long long off;
  if (i < 4194304)       { src = q;  off = 0; }
  else if (i < 8388608)  { src = k;  off = 4194304; }
  else if (i < 12582912) { src = v;  off = 8388608; }
  else if (i < 13631488) { src = qw; off = 12582912; }
  else if (i < 14680064) { src = kw; off = 13631488; }
  else if (i < 15728640) { src = vw; off = 14680064; }
  else                   { src = ow; off = 15728640; }
  f32x4 val = *(const f32x4*)(src + (i - off));
  f16x4 h;
#pragma unroll
  for (int r = 0; r < 4; ++r) h[r] = (f16)val[r];
  *(f16x4*)(xf + i) = h;
}

// ---------------- GEMM helpers: 128x128 tile, K-step 64, stride-1024 sources ----------------
__device__ __forceinline__ void stage64(f16* lds, const f16* g, int row0, int kc, int tid) {
#pragma unroll
  for (int j = 0; j < 4; ++j) {
    int chunk = j * 256 + tid;
    int r = chunk >> 3, cpos = chunk & 7;
    int csrc = cpos ^ (r & 7);
    gload16((char*)lds + chunk * 16,
            (const char*)(g + (size_t)(row0 + r) * 1024 + kc) + csrc * 16);
  }
}

__device__ __forceinline__ f16x8 frag64(const f16* lds, int row, int c) {
  int pos = c ^ (row & 7);
  return *(const f16x8*)((const char*)lds + row * 128 + pos * 16);
}

__device__ __forceinline__ void gemm_core(const f16* A, const f16* X, int o0, int t0, int tid,
                                          f16* sA, f16* sB, f32x4 acc[4][4]) {
  int wid = tid >> 6, lane = tid & 63;
  int wm = wid >> 1, wn = wid & 1, g = lane >> 4, r15 = lane & 15;
  for (int kc = 0; kc < 1024; kc += 64) {
    __syncthreads();
    stage64(sA, A, o0, kc, tid);
    stage64(sB, X, t0, kc, tid);
    __syncthreads();
    f16x8 a0[4], a1[4], x0[4], x1[4];
#pragma unroll
    for (int f = 0; f < 4; ++f) {
      int ra = wm * 64 + f * 16 + r15;
      int rx = wn * 64 + f * 16 + r15;
      a0[f] = frag64(sA, ra, g);
      a1[f] = frag64(sA, ra, 4 + g);
      x0[f] = frag64(sB, rx, g);
      x1[f] = frag64(sB, rx, 4 + g);
    }
#pragma unroll
    for (int fm = 0; fm < 4; ++fm)
#pragma unroll
      for (int fn = 0; fn < 4; ++fn) {
        acc[fm][fn] = MFMAH(a0[fm], x0[fn], acc[fm][fn]);
        acc[fm][fn] = MFMAH(a1[fm], x1[fn], acc[fm][fn]);
      }
  }
}

// ---------------- fused Q/K/V projections (blockIdx.z = 0:Q, 1:K, 2:V) ----------------
__global__ __launch_bounds__(256, 3) void gemm_qkv(const f16* __restrict__ xf,
                                                   const float* __restrict__ q_b, const float* __restrict__ k_b,
                                                   const float* __restrict__ v_b,
                                                   f16* __restrict__ Qf, f16* __restrict__ Kf,
                                                   f16* __restrict__ VT2) {
  __shared__ f16 sA[8192], sB[8192];
  int z = blockIdx.z;
  int tid = threadIdx.x;
  int wid = tid >> 6, lane = tid & 63;
  int wm = wid >> 1, wn = wid & 1, g = lane >> 4, r15 = lane & 15;
  f32x4 acc[4][4] = {};
  if (z == 2) {
    const f16* X = xf + 8388608;   // value
    const f16* W = xf + 14680064;  // v_w
    int o0 = blockIdx.x * 128, t0 = blockIdx.y * 128;
    gemm_core(X, W, t0, o0, tid, sA, sB, acc);
#pragma unroll
    for (int fm = 0; fm < 4; ++fm)
#pragma unroll
      for (int fn = 0; fn < 4; ++fn) {
        int tb = t0 + wm * 64 + fm * 16 + 4 * g;
        int o  = o0 + wn * 64 + fn * 16 + r15;
        int bb = tb >> 11, tl = tb & 2047, hh = o >> 6, dd = o & 63;
        int ch = tl >> 5, c = tl & 31;
        int slotbase = (c < 16) ? ((c >> 2) << 3) : ((((c - 16) >> 2) << 3) + 4);
        float bo = v_b[o];
        f16x4 v4;
#pragma unroll
        for (int r = 0; r < 4; ++r) v4[r] = (f16)(acc[fm][fn][r] + bo);
        *(f16x4*)(VT2 + ((((size_t)bb * 16 + hh) * 64 + ch) * 64 + dd) * 32 + slotbase) = v4;
      }
  } else {
    const f16* A = xf + (z ? 13631488 : 12582912);
    const f16* X = xf + (z ? 4194304 : 0);
    const float* bias = z ? k_b : q_b;
    f16* Yf = z ? Kf : Qf;
    float scale = z ? 1.0f : 0.125f;
    int o0 = blockIdx.x * 128, t0 = blockIdx.y * 128;
    gemm_core(A, X, o0, t0, tid, sA, sB, acc);
#pragma unroll
    for (int fm = 0; fm < 4; ++fm)
#pragma unroll
      for (int fn = 0; fn < 4; ++fn) {
        int ob = o0 + wm * 64 + fm * 16 + 4 * g;
        int t  = t0 + wn * 64 + fn * 16 + r15;
        int bb = t >> 11, tl = t & 2047, hh = ob >> 6, dd = ob & 63;
        size_t base = (((size_t)bb * 16 + hh) * 2048 + tl) * 64 + dd;
        f16x4 vh;
#pragma unroll
        for (int r = 0; r < 4; ++r)
          vh[r] = (f16)((acc[fm][fn][r] + bias[ob + r]) * scale);
        *(f16x4*)(Yf + base) = vh;
      }
  }
}

// ---------------- O projection: Out[t][o] = A[t][:].o_w[o][:] + b, f32 ----------------
__global__ __launch_bounds__(256, 3) void gemm_o(const f16* __restrict__ xf, const f16* __restrict__ Abuf,
                                                 const float* __restrict__ o_b, float* __restrict__ OutF) {
  __shared__ f16 sA[8192], sB[8192];
  const f16* A = xf + 15728640;  // o_w
  int tid = threadIdx.x;
  int o0 = blockIdx.x * 128, t0 = blockIdx.y * 128;
  int wid = tid >> 6, lane = tid & 63;
  int wm = wid >> 1, wn = wid & 1, g = lane >> 4, r15 = lane & 15;
  f32x4 acc[4][4] = {};
  gemm_core(A, Abuf, o0, t0, tid, sA, sB, acc);
#pragma unroll
  for (int fm = 0; fm < 4; ++fm)
#pragma unroll
    for (int fn = 0; fn < 4; ++fn) {
      int ob = o0 + wm * 64 + fm * 16 + 4 * g;
      int t  = t0 + wn * 64 + fn * 16 + r15;
      f32x4 v;
#pragma unroll
      for (int r = 0; r < 4; ++r) v[r] = acc[fm][fn][r] + o_b[ob + r];
      *(f32x4*)(OutF + (size_t)t * 1024 + ob) = v;
    }
}

// ---------------- fused attention (v20: autonomous waves, zero barriers) ----------------
// 1024 blocks x 256 thr (4 waves). Wave task = bswz*4+wid -> (bh, 16 q-rows), ALL 2048 k.
// Pass A: QK^T + masked exp -> row sums (P discarded); in-wave shfl reduce -> rz.
// Pass B: recompute QK per 8-tile group -> pstage transpose -> 512B NT stores + PV.
__global__ __launch_bounds__(256, 5) void attn_kernel(
    const f16* __restrict__ Qf, const f16* __restrict__ Kf,
    const f16* __restrict__ VT2, const int* __restrict__ mask,
    float* __restrict__ wout, f16* __restrict__ Abuf) {
  __shared__ char pstage[4][4224];  // per-wave transpose buffer (16 rows x 264 B)
  int tid = threadIdx.x;
  int wid = tid >> 6, lane = tid & 63;
  int g = lane >> 4, r15 = lane & 15;
  int c5 = lane & 31, hi5 = lane >> 5;
  // Block-level XCD swizzle (1024 blocks): each XCD gets a contiguous 128-block slab (4 bh).
  int bid = blockIdx.x;
  int bswz = (bid & 7) * 128 + (bid >> 3);
  int task = bswz * 4 + wid;        // 0..4095
  int qt = task & 127, bh = task >> 7;
  int b = bh >> 4, h = bh & 15;
  int q0 = qt * 16;

  // Q fragments (B-operand: col = q = lane&15). 1/8 scale folded into Qf.
  const f16* qp = Qf + ((size_t)bh * 2048 + q0 + r15) * 64 + 8 * g;
  f16x8 qh0 = *(const f16x8*)(qp);
  f16x8 qh1 = *(const f16x8*)(qp + 32);

  // K source: tile s at kbase + s*1024 (lane reads k=s*16+r15, d=8g..8g+8 and +32)
  const f16* kbase = Kf + ((size_t)bh * 2048 + r15) * 64 + 8 * g;
  const int* mp = mask + b * 2048 + 4 * g;  // tile s: int4 at mp + s*16 (k=s*16+4g+r)

  // ---- pass A: row sums (2 tiles/iter, 1-iter prefetch, clamped tail) ----
  float psum = 0.f;
  f16x8 a0 = *(const f16x8*)(kbase);
  f16x8 a1 = *(const f16x8*)(kbase + 32);
  f16x8 b0 = *(const f16x8*)(kbase + 1024);
  f16x8 b1 = *(const f16x8*)(kbase + 1024 + 32);
  int4 m0 = *(const int4*)(mp);
  int4 m1 = *(const int4*)(mp + 16);
  for (int s2 = 0; s2 < 64; ++s2) {
    int sn = (s2 < 63) ? (2 * s2 + 2) : 126;  // clamped prefetch base
    f16x8 na0 = *(const f16x8*)(kbase + (size_t)sn * 1024);
    f16x8 na1 = *(const f16x8*)(kbase + (size_t)sn * 1024 + 32);
    f16x8 nb0 = *(const f16x8*)(kbase + (size_t)(sn + 1) * 1024);
    f16x8 nb1 = *(const f16x8*)(kbase + (size_t)(sn + 1) * 1024 + 32);
    int4 nm0 = *(const int4*)(mp + sn * 16);
    int4 nm1 = *(const int4*)(mp + (sn + 1) * 16);
    f32x4 s0v = {0.f, 0.f, 0.f, 0.f}, s1v = {0.f, 0.f, 0.f, 0.f};
    s0v = MFMAH(a0, qh0, s0v);
    s1v = MFMAH(b0, qh0, s1v);
    s0v = MFMAH(a1, qh1, s0v);
    s1v = MFMAH(b1, qh1, s1v);
    psum += (m0.x ? 0.f : __expf(s0v[0])) + (m0.y ? 0.f : __expf(s0v[1])) +
            (m0.z ? 0.f : __expf(s0v[2])) + (m0.w ? 0.f : __expf(s0v[3]));
    psum += (m1.x ? 0.f : __expf(s1v[0])) + (m1.y ? 0.f : __expf(s1v[1])) +
            (m1.z ? 0.f : __expf(s1v[2])) + (m1.w ? 0.f : __expf(s1v[3]));
    a0 = na0; a1 = na1; b0 = nb0; b1 = nb1;
    m0 = nm0; m1 = nm1;
  }
  // in-wave reduce over the 4 lanes sharing q=r15 -> every lane holds z(q=r15)
  psum += __shfl_xor(psum, 16);
  psum += __shfl_xor(psum, 32);
  float rzv = (psum > 0.f) ? 1.0f / psum : 0.0f;
  // rz for store rows (row = 2i+hi5) and PV rows (q = 4g+r)
  float rr[8];
#pragma unroll
  for (int i = 0; i < 8; ++i) rr[i] = __shfl(rzv, 2 * i + hi5);
  float rq0 = __shfl(rzv, 4 * g + 0);
  float rq1 = __shfl(rzv, 4 * g + 1);
  float rq2 = __shfl(rzv, 4 * g + 2);
  float rq3 = __shfl(rzv, 4 * g + 3);

  // ---- pass B: recompute -> pstage transpose -> NT stores + PV, per 8-tile group ----
  char* pst = &pstage[wid][0];
  float* wrow = wout + ((size_t)bh * 2048 + q0) * 2048;
  const f16* vbase = VT2 + ((size_t)bh * 64 * 64 + r15) * 32 + g * 8;  // + ch*2048 + dt*512
  f32x4 acc0 = {}, acc1 = {}, acc2 = {}, acc3 = {};

  for (int grp = 0; grp < 16; ++grp) {
    int s0 = grp * 8;
    f16x4 P8[8];
    f16x8 ka0 = *(const f16x8*)(kbase + (size_t)s0 * 1024);
    f16x8 ka1 = *(const f16x8*)(kbase + (size_t)s0 * 1024 + 32);
    int4 km = *(const int4*)(mp + s0 * 16);
#pragma unroll
    for (int t8 = 0; t8 < 8; ++t8) {
      int s = s0 + t8;
      int sn = (s < 127) ? (s + 1) : 127;
      f16x8 na0 = *(const f16x8*)(kbase + (size_t)sn * 1024);
      f16x8 na1 = *(const f16x8*)(kbase + (size_t)sn * 1024 + 32);
      int4 nm = *(const int4*)(mp + sn * 16);
      f32x4 sc = {0.f, 0.f, 0.f, 0.f};
      sc = MFMAH(ka0, qh0, sc);
      sc = MFMAH(ka1, qh1, sc);
      f16x4 pk;
      pk[0] = (f16)(km.x ? 0.f : __expf(sc[0]));
      pk[1] = (f16)(km.y ? 0.f : __expf(sc[1]));
      pk[2] = (f16)(km.z ? 0.f : __expf(sc[2]));
      pk[3] = (f16)(km.w ? 0.f : __expf(sc[3]));
      P8[t8] = pk;
      ka0 = na0; ka1 = na1; km = nm;
    }
    // transpose through wave-private LDS (byte(k) = 2k within each 264B row)
#pragma unroll
    for (int t8 = 0; t8 < 8; ++t8)
      *(f16x4*)(pst + r15 * 264 + t8 * 32 + g * 8) = P8[t8];
    asm volatile("s_waitcnt lgkmcnt(0)" ::: "memory");
    // 8 contiguous 512B-row NT store instrs (2 rows each), normalized
#pragma unroll
    for (int i = 0; i < 8; ++i) {
      int row = 2 * i + hi5;
      f16x4 pv4 = *(const f16x4*)(pst + row * 264 + c5 * 8);
      f32x4 wv;
#pragma unroll
      for (int r = 0; r < 4; ++r) wv[r] = (float)pv4[r] * rr[i];
      __builtin_nontemporal_store(wv,
          (f32x4*)(wrow + (size_t)row * 2048 + grp * 128 + 4 * c5));
    }
    // PV for this group's 4 k-chunks (unnormalized P; rz applied at the end)
#pragma unroll
    for (int p = 0; p < 4; ++p) {
      const f16* vb = vbase + (size_t)(grp * 4 + p) * 2048;
      f16x8 v0 = *(const f16x8*)(vb);
      f16x8 v1 = *(const f16x8*)(vb + 512);
      f16x8 v2 = *(const f16x8*)(vb + 1024);
      f16x8 v3 = *(const f16x8*)(vb + 1536);
      f16x8 af = __builtin_shufflevector(P8[2 * p], P8[2 * p + 1], 0, 1, 2, 3, 4, 5, 6, 7);
      acc0 = MFMAH(af, v0, acc0);
      acc1 = MFMAH(af, v1, acc1);
      acc2 = MFMAH(af, v2, acc2);
      acc3 = MFMAH(af, v3, acc3);
    }
  }

  // ---- final: Abuf (f16 [B,T,C]); q = 4g+r, d = dt*16 + r15 ----
  {
    f16* ab = Abuf + ((size_t)b * 2048 + q0 + 4 * g) * 1024 + h * 64 + r15;
    ab[0 * 1024 + 0]  = (f16)(acc0[0] * rq0);
    ab[0 * 1024 + 16] = (f16)(acc1[0] * rq0);
    ab[0 * 1024 + 32] = (f16)(acc2[0] * rq0);
    ab[0 * 1024 + 48] = (f16)(acc3[0] * rq0);
    ab[1 * 1024 + 0]  = (f16)(acc0[1] * rq1);
    ab[1 * 1024 + 16] = (f16)(acc1[1] * rq1);
    ab[1 * 1024 + 32] = (f16)(acc2[1] * rq1);
    ab[1 * 1024 + 48] = (f16)(acc3[1] * rq1);
    ab[2 * 1024 + 0]  = (f16)(acc0[2] * rq2);
    ab[2 * 1024 + 16] = (f16)(acc1[2] * rq2);
    ab[2 * 1024 + 32] = (f16)(acc2[2] * rq2);
    ab[2 * 1024 + 48] = (f16)(acc3[2] * rq2);
    ab[3 * 1024 + 0]  = (f16)(acc0[3] * rq3);
    ab[3 * 1024 + 16] = (f16)(acc1[3] * rq3);
    ab[3 * 1024 + 32] = (f16)(acc2[3] * rq3);
    ab[3 * 1024 + 48] = (f16)(acc3[3] * rq3);
  }
}

extern "C" void kernel_launch(void* const* d_in, const int* in_sizes, int n_in,
                              void* d_out, int out_size, void* d_ws, size_t ws_size,
                              hipStream_t stream) {
  const float* query = (const float*)d_in[0];
  const float* key_i = (const float*)d_in[1];
  const float* value = (const float*)d_in[2];
  const float* q_w = (const float*)d_in[3];
  const float* q_b = (const float*)d_in[4];
  const float* k_w = (const float*)d_in[5];
  const float* k_b = (const float*)d_in[6];
  const float* v_w = (const float*)d_in[7];
  const float* v_b = (const float*)d_in[8];
  const float* o_w = (const float*)d_in[9];
  const float* o_b = (const float*)d_in[10];
  const int* mask = (const int*)d_in[11];
  float* out = (float*)d_out;
  float* wout = out + 4194304;  // weights output region

  // layout: [xf 33.6MB][Qf 8.4MB][Kf 8.4MB][VT2 8.4MB][Abuf 8.4MB] = 67 MB
  const size_t XFB = 16777216ull * 2;
  const size_t QB = 4194304ull * 2;
  if (ws_size < XFB + 4 * QB) return;
  f16* xf   = (f16*)d_ws;
  f16* Qf   = (f16*)((char*)d_ws + XFB);
  f16* Kf   = (f16*)((char*)d_ws + XFB + QB);
  f16* VT2  = (f16*)((char*)d_ws + XFB + 2 * QB);
  f16* Abuf = (f16*)((char*)d_ws + XFB + 3 * QB);

  conv_f16<<<16384, 256, 0, stream>>>(query, key_i, value, q_w, k_w, v_w, o_w, xf);
  gemm_qkv<<<dim3(8, 32, 3), 256, 0, stream>>>(xf, q_b, k_b, v_b, Qf, Kf, VT2);
  attn_kernel<<<1024, 256, 0, stream>>>(Qf, Kf, VT2, mask, wout, Abuf);
  gemm_o<<<dim3(8, 32), 256, 0, stream>>>(xf, Abuf, o_b, out);
}

// Round 20
// 248.075 us; speedup vs baseline: 1.8411x; 1.8411x over previous
//
#include <hip/hip_runtime.h>
#include <math.h>

// WheelMultiheadAttention on MI355X (gfx950) — v21 = v14 restored (best known, 247.2us).
// conv_f16 -> fused QKV projection GEMMs (BK=64) -> attn (async-LDS K staging, register P,
// block rz reduce, PV + transpose-staged contiguous 512B NT weight stores, XCD swizzle)
// -> O projection. v18 probe: isolated NT write of the 537MB weights region = 5.74 TB/s;
// 7 structural attempts to recover the attn phase-serialization gap all regressed.
// B=2 T=2048 C=1024 H=16 D=64. Outputs: out [2,2048,1024] f32, weights [2,16,2048,2048] f32.

typedef _Float16 f16;
typedef _Float16 f16x2 __attribute__((ext_vector_type(2)));
typedef _Float16 f16x4 __attribute__((ext_vector_type(4)));
typedef _Float16 f16x8 __attribute__((ext_vector_type(8)));
typedef float  f32x2  __attribute__((ext_vector_type(2)));
typedef float  f32x4  __attribute__((ext_vector_type(4)));

#define MFMAH(a, b, c)  __builtin_amdgcn_mfma_f32_16x16x32_f16((a), (b), (c), 0, 0, 0)

__device__ __forceinline__ void gload16(void* lds, const void* g) {
  __builtin_amdgcn_global_load_lds((__attribute__((address_space(1))) void*)(g),
                                   (__attribute__((address_space(3))) void*)(lds),
                                   16, 0, 0);
}

// ---------------- fused f32 -> f16 convert (query|key|value|q_w|k_w|v_w|o_w) ----------------
__global__ __launch_bounds__(256) void conv_f16(const float* __restrict__ q, const float* __restrict__ k,
                                                const float* __restrict__ v, const float* __restrict__ qw,
                                                const float* __restrict__ kw, const float* __restrict__ vw,
                                                const float* __restrict__ ow, f16* __restrict__ xf) {
  long long i = ((long long)blockIdx.x * 256 + threadIdx.x) * 4;
  const float* src;
  long long off;
  if (i < 4194304)       { src = q;  off = 0; }
  else if (i < 8388608)  { src = k;  off = 4194304; }
  else if (i < 12582912) { src = v;  off = 8388608; }
  else if (i < 13631488) { src = qw; off = 12582912; }
  else if (i < 14680064) { src = kw; off = 13631488; }
  else if (i < 15728640) { src = vw; off = 14680064; }
  else                   { src = ow; off = 15728640; }
  f32x4 val = *(const f32x4*)(src + (i - off));
  f16x4 h;
#pragma unroll
  for (int r = 0; r < 4; ++r) h[r] = (f16)val[r];
  *(f16x4*)(xf + i) = h;
}

// ---------------- GEMM helpers: 128x128 tile, K-step 64, stride-1024 sources ----------------
__device__ __forceinline__ void stage64(f16* lds, const f16* g, int row0, int kc, int tid) {
#pragma unroll
  for (int j = 0; j < 4; ++j) {
    int chunk = j * 256 + tid;
    int r = chunk >> 3, cpos = chunk & 7;
    int csrc = cpos ^ (r & 7);
    gload16((char*)lds + chunk * 16,
            (const char*)(g + (size_t)(row0 + r) * 1024 + kc) + csrc * 16);
  }
}

__device__ __forceinline__ f16x8 frag64(const f16* lds, int row, int c) {
  int pos = c ^ (row & 7);
  return *(const f16x8*)((const char*)lds + row * 128 + pos * 16);
}

__device__ __forceinline__ void gemm_core(const f16* A, const f16* X, int o0, int t0, int tid,
                                          f16* sA, f16* sB, f32x4 acc[4][4]) {
  int wid = tid >> 6, lane = tid & 63;
  int wm = wid >> 1, wn = wid & 1, g = lane >> 4, r15 = lane & 15;
  for (int kc = 0; kc < 1024; kc += 64) {
    __syncthreads();
    stage64(sA, A, o0, kc, tid);
    stage64(sB, X, t0, kc, tid);
    __syncthreads();
    f16x8 a0[4], a1[4], x0[4], x1[4];
#pragma unroll
    for (int f = 0; f < 4; ++f) {
      int ra = wm * 64 + f * 16 + r15;
      int rx = wn * 64 + f * 16 + r15;
      a0[f] = frag64(sA, ra, g);
      a1[f] = frag64(sA, ra, 4 + g);
      x0[f] = frag64(sB, rx, g);
      x1[f] = frag64(sB, rx, 4 + g);
    }
#pragma unroll
    for (int fm = 0; fm < 4; ++fm)
#pragma unroll
      for (int fn = 0; fn < 4; ++fn) {
        acc[fm][fn] = MFMAH(a0[fm], x0[fn], acc[fm][fn]);
        acc[fm][fn] = MFMAH(a1[fm], x1[fn], acc[fm][fn]);
      }
  }
}

// ---------------- fused Q/K/V projections (blockIdx.z = 0:Q, 1:K, 2:V) ----------------
__global__ __launch_bounds__(256, 3) void gemm_qkv(const f16* __restrict__ xf,
                                                   const float* __restrict__ q_b, const float* __restrict__ k_b,
                                                   const float* __restrict__ v_b,
                                                   f16* __restrict__ Qf, f16* __restrict__ Kf,
                                                   f16* __restrict__ VT2) {
  __shared__ f16 sA[8192], sB[8192];
  int z = blockIdx.z;
  int tid = threadIdx.x;
  int wid = tid >> 6, lane = tid & 63;
  int wm = wid >> 1, wn = wid & 1, g = lane >> 4, r15 = lane & 15;
  f32x4 acc[4][4] = {};
  if (z == 2) {
    const f16* X = xf + 8388608;   // value
    const f16* W = xf + 14680064;  // v_w
    int o0 = blockIdx.x * 128, t0 = blockIdx.y * 128;
    gemm_core(X, W, t0, o0, tid, sA, sB, acc);
#pragma unroll
    for (int fm = 0; fm < 4; ++fm)
#pragma unroll
      for (int fn = 0; fn < 4; ++fn) {
        int tb = t0 + wm * 64 + fm * 16 + 4 * g;
        int o  = o0 + wn * 64 + fn * 16 + r15;
        int bb = tb >> 11, tl = tb & 2047, hh = o >> 6, dd = o & 63;
        int ch = tl >> 5, c = tl & 31;
        int slotbase = (c < 16) ? ((c >> 2) << 3) : ((((c - 16) >> 2) << 3) + 4);
        float bo = v_b[o];
        f16x4 v4;
#pragma unroll
        for (int r = 0; r < 4; ++r) v4[r] = (f16)(acc[fm][fn][r] + bo);
        *(f16x4*)(VT2 + ((((size_t)bb * 16 + hh) * 64 + ch) * 64 + dd) * 32 + slotbase) = v4;
      }
  } else {
    const f16* A = xf + (z ? 13631488 : 12582912);
    const f16* X = xf + (z ? 4194304 : 0);
    const float* bias = z ? k_b : q_b;
    f16* Yf = z ? Kf : Qf;
    float scale = z ? 1.0f : 0.125f;
    int o0 = blockIdx.x * 128, t0 = blockIdx.y * 128;
    gemm_core(A, X, o0, t0, tid, sA, sB, acc);
#pragma unroll
    for (int fm = 0; fm < 4; ++fm)
#pragma unroll
      for (int fn = 0; fn < 4; ++fn) {
        int ob = o0 + wm * 64 + fm * 16 + 4 * g;
        int t  = t0 + wn * 64 + fn * 16 + r15;
        int bb = t >> 11, tl = t & 2047, hh = ob >> 6, dd = ob & 63;
        size_t base = (((size_t)bb * 16 + hh) * 2048 + tl) * 64 + dd;
        f16x4 vh;
#pragma unroll
        for (int r = 0; r < 4; ++r)
          vh[r] = (f16)((acc[fm][fn][r] + bias[ob + r]) * scale);
        *(f16x4*)(Yf + base) = vh;
      }
  }
}

// ---------------- O projection: Out[t][o] = A[t][:].o_w[o][:] + b, f32 ----------------
__global__ __launch_bounds__(256, 3) void gemm_o(const f16* __restrict__ xf, const f16* __restrict__ Abuf,
                                                 const float* __restrict__ o_b, float* __restrict__ OutF) {
  __shared__ f16 sA[8192], sB[8192];
  const f16* A = xf + 15728640;  // o_w
  int tid = threadIdx.x;
  int o0 = blockIdx.x * 128, t0 = blockIdx.y * 128;
  int wid = tid >> 6, lane = tid & 63;
  int wm = wid >> 1, wn = wid & 1, g = lane >> 4, r15 = lane & 15;
  f32x4 acc[4][4] = {};
  gemm_core(A, Abuf, o0, t0, tid, sA, sB, acc);
#pragma unroll
  for (int fm = 0; fm < 4; ++fm)
#pragma unroll
    for (int fn = 0; fn < 4; ++fn) {
      int ob = o0 + wm * 64 + fm * 16 + 4 * g;
      int t  = t0 + wn * 64 + fn * 16 + r15;
      f32x4 v;
#pragma unroll
      for (int r = 0; r < 4; ++r) v[r] = acc[fm][fn][r] + o_b[ob + r];
      *(f32x4*)(OutF + (size_t)t * 1024 + ob) = v;
    }
}

// ---------------- fused attention (v14/v12: NT stores + XCD swizzle) ----------------
__global__ __launch_bounds__(512, 6) void attn_kernel(
    const f16* __restrict__ Qf, const f16* __restrict__ Kf,
    const f16* __restrict__ VT2, const int* __restrict__ mask,
    float* __restrict__ wout, f16* __restrict__ Abuf) {
  __shared__ char smemA[8][4224];  // per-wave: phase1 K dbuf (2x2048B) -> phase2 pstage
  __shared__ f16 pvh[8][16][72];   // PV partials f16
  __shared__ float ps[128];        // row-sum partials [q][wave]
  __shared__ float rz[16];
  int tid = threadIdx.x;
  int wid = tid >> 6, lane = tid & 63;
  int g = lane >> 4, r15 = lane & 15;
  int bid = blockIdx.x;
  int swz = (bid & 7) * 512 + (bid >> 3);
  int qt = swz & 127, bh = swz >> 7;
  int b = bh >> 4, h = bh & 15;
  int q0 = qt * 16;

  const f16* qp = Qf + ((size_t)bh * 2048 + q0 + r15) * 64 + 8 * g;
  f16x8 qh0 = *(const f16x8*)(qp);
  f16x8 qh1 = *(const f16x8*)(qp + 32);

  const int* mp = mask + b * 2048 + wid * 256 + 4 * g;
  unsigned long long mb = 0;
#pragma unroll
  for (int t = 0; t < 16; ++t) {
    int4 ma = *(const int4*)(mp + t * 16);
    mb |= ((ma.x ? 1ull : 0ull) << (4 * t)) | ((ma.y ? 1ull : 0ull) << (4 * t + 1)) |
          ((ma.z ? 1ull : 0ull) << (4 * t + 2)) | ((ma.w ? 1ull : 0ull) << (4 * t + 3));
  }

  f16* kb0 = (f16*)&smemA[wid][0];
  f16* kb1 = (f16*)&smemA[wid][2048];
  const f16* ksrcA = Kf + ((size_t)bh * 2048 + wid * 256 + (lane >> 3)) * 64 +
                     (((lane & 7) ^ ((lane >> 3) & 7)) * 8);
  const f16* ksrcB = ksrcA + 8 * 64;

  gload16(kb0, ksrcA);
  gload16(kb0 + 512, ksrcB);
  gload16(kb1, ksrcA + 1024);
  gload16(kb1 + 512, ksrcB + 1024);
  asm volatile("s_waitcnt vmcnt(2)" ::: "memory");
  int key = r15 & 7;
  f16x8 c0 = *(const f16x8*)(kb0 + r15 * 64 + ((g ^ key) * 8));
  f16x8 c1 = *(const f16x8*)(kb0 + r15 * 64 + (((g + 4) ^ key) * 8));

  float psum = 0.f;
  f16x4 p16[16];
#pragma unroll
  for (int s = 0; s < 16; ++s) {
    if (s < 14) {
      asm volatile("s_waitcnt lgkmcnt(0)" ::: "memory");
      f16* nb = (s & 1) ? kb1 : kb0;
      gload16(nb, ksrcA + (s + 2) * 1024);
      gload16(nb + 512, ksrcB + (s + 2) * 1024);
    }
    f16x8 n0, n1;
    if (s < 15) {
      if (s < 14) asm volatile("s_waitcnt vmcnt(2)" ::: "memory");
      else        asm volatile("s_waitcnt vmcnt(0)" ::: "memory");
      const f16* nt = ((s + 1) & 1) ? kb1 : kb0;
      n0 = *(const f16x8*)(nt + r15 * 64 + ((g ^ key) * 8));
      n1 = *(const f16x8*)(nt + r15 * 64 + (((g + 4) ^ key) * 8));
    }
    f32x4 sc = {0.f, 0.f, 0.f, 0.f};
    sc = MFMAH(c0, qh0, sc);
    sc = MFMAH(c1, qh1, sc);
    f16x4 pk;
#pragma unroll
    for (int r = 0; r < 4; ++r) {
      float e = ((mb >> (4 * s + r)) & 1) ? 0.f : __expf(sc[r]);
      psum += e;
      pk[r] = (f16)e;
    }
    p16[s] = pk;
    c0 = n0;
    c1 = n1;
  }

  psum += __shfl_xor(psum, 16);
  psum += __shfl_xor(psum, 32);
  if (lane < 16) ps[lane * 8 + wid] = psum;
  __syncthreads();

  if (tid < 128) {
    float z = ps[tid];
#pragma unroll
    for (int m = 1; m <= 4; m <<= 1) z += __shfl_xor(z, m);
    if ((tid & 7) == 0) rz[tid >> 3] = (z > 0.f) ? 1.0f / z : 0.0f;
  }
  __syncthreads();

  f32x4 acc[4] = {};
  {
    char* pst = &smemA[wid][0];
    int c5 = lane & 31, hi5 = lane >> 5;
    float* wrowbase = wout + ((size_t)bh * 2048 + q0) * 2048 + wid * 256;
    const f16* vb = VT2 + (((size_t)bh * 64 + wid * 8) * 64 + r15) * 32 + g * 8;
    f16x8 v0 = *(const f16x8*)(vb);
    f16x8 v1 = *(const f16x8*)(vb + 512);
    f16x8 v2 = *(const f16x8*)(vb + 1024);
    f16x8 v3 = *(const f16x8*)(vb + 1536);
#pragma unroll
    for (int t = 0; t < 8; ++t) {
      f16x8 n0, n1, n2, n3;
      if (t < 7) {
        const f16* nvb = vb + (t + 1) * 2048;
        n0 = *(const f16x8*)(nvb);
        n1 = *(const f16x8*)(nvb + 512);
        n2 = *(const f16x8*)(nvb + 1024);
        n3 = *(const f16x8*)(nvb + 1536);
      }
      if (t == 0 || t == 4) {
        int hb = (t >> 2) * 8;
#pragma unroll
        for (int s2 = 0; s2 < 8; ++s2)
          *(f16x4*)(pst + r15 * 264 + s2 * 32 + g * 8) = p16[hb + s2];
        asm volatile("s_waitcnt lgkmcnt(0)" ::: "memory");
      }
      {
        int hh2 = t >> 2, rbase = (t & 3) * 4;
#pragma unroll
        for (int u = 0; u < 2; ++u) {
          int row = rbase + 2 * u + hi5;
          f16x4 pv4 = *(const f16x4*)(pst + row * 264 + c5 * 8);
          float rzr = rz[row];
          f32x4 wv;
#pragma unroll
          for (int r = 0; r < 4; ++r) wv[r] = (float)pv4[r] * rzr;
          __builtin_nontemporal_store(wv,
              (f32x4*)(wrowbase + (size_t)row * 2048 + hh2 * 128 + 4 * c5));
        }
      }
      f16x8 af = __builtin_shufflevector(p16[2 * t], p16[2 * t + 1], 0, 1, 2, 3, 4, 5, 6, 7);
      acc[0] = MFMAH(af, v0, acc[0]);
      acc[1] = MFMAH(af, v1, acc[1]);
      acc[2] = MFMAH(af, v2, acc[2]);
      acc[3] = MFMAH(af, v3, acc[3]);
      v0 = n0; v1 = n1; v2 = n2; v3 = n3;
    }
#pragma unroll
    for (int dt = 0; dt < 4; ++dt)
#pragma unroll
      for (int r = 0; r < 4; ++r)
        pvh[wid][4 * g + r][dt * 16 + r15] = (f16)acc[dt][r];
  }
  __syncthreads();

  {
    int q = tid >> 5, d = (tid & 31) * 2;
    float a0 = 0.f, a1 = 0.f;
#pragma unroll
    for (int w8 = 0; w8 < 8; ++w8) {
      f16x2 v = *(const f16x2*)&pvh[w8][q][d];
      a0 += (float)v[0];
      a1 += (float)v[1];
    }
    float rzq = rz[q];
    f16x2 o2 = {(f16)(a0 * rzq), (f16)(a1 * rzq)};
    *(f16x2*)(Abuf + ((size_t)b * 2048 + q0 + q) * 1024 + h * 64 + d) = o2;
  }
}

extern "C" void kernel_launch(void* const* d_in, const int* in_sizes, int n_in,
                              void* d_out, int out_size, void* d_ws, size_t ws_size,
                              hipStream_t stream) {
  const float* query = (const float*)d_in[0];
  const float* key_i = (const float*)d_in[1];
  const float* value = (const float*)d_in[2];
  const float* q_w = (const float*)d_in[3];
  const float* q_b = (const float*)d_in[4];
  const float* k_w = (const float*)d_in[5];
  const float* k_b = (const float*)d_in[6];
  const float* v_w = (const float*)d_in[7];
  const float* v_b = (const float*)d_in[8];
  const float* o_w = (const float*)d_in[9];
  const float* o_b = (const float*)d_in[10];
  const int* mask = (const int*)d_in[11];
  float* out = (float*)d_out;
  float* wout = out + 4194304;  // weights output region

  // layout: [xf 33.6MB][Qf 8.4MB][Kf 8.4MB][VT2 8.4MB][Abuf 8.4MB] = 67 MB
  const size_t XFB = 16777216ull * 2;
  const size_t QB = 4194304ull * 2;
  if (ws_size < XFB + 4 * QB) return;
  f16* xf   = (f16*)d_ws;
  f16* Qf   = (f16*)((char*)d_ws + XFB);
  f16* Kf   = (f16*)((char*)d_ws + XFB + QB);
  f16* VT2  = (f16*)((char*)d_ws + XFB + 2 * QB);
  f16* Abuf = (f16*)((char*)d_ws + XFB + 3 * QB);

  conv_f16<<<16384, 256, 0, stream>>>(query, key_i, value, q_w, k_w, v_w, o_w, xf);
  gemm_qkv<<<dim3(8, 32, 3), 256, 0, stream>>>(xf, q_b, k_b, v_b, Qf, Kf, VT2);
  attn_kernel<<<4096, 512, 0, stream>>>(Qf, Kf, VT2, mask, wout, Abuf);
  gemm_o<<<dim3(8, 32), 256, 0, stream>>>(xf, Abuf, o_b, out);
}